// Round 1
// baseline (284.879 us; speedup 1.0000x reference)
//
#include <hip/hip_runtime.h>
#include <hip/hip_bf16.h>

typedef __attribute__((ext_vector_type(8))) short short8;
typedef __attribute__((ext_vector_type(4))) float f32x4;

#define NR 256
#define CC 256

__device__ __forceinline__ unsigned short f2bf(float x) {
    union { float f; unsigned int u; } v; v.f = x;
    unsigned int r = v.u + 0x7FFFu + ((v.u >> 16) & 1u);
    return (unsigned short)(r >> 16);
}
__device__ __forceinline__ float bf2f(unsigned short x) {
    union { float f; unsigned int u; } v; v.u = ((unsigned int)x) << 16;
    return v.f;
}

// ---------------- Qp = Q @ Wq + bq : [4][256] ----------------
__global__ __launch_bounds__(256) void qp_kernel(
    const float* __restrict__ Q, const float* __restrict__ Wq,
    const float* __restrict__ bq, float* __restrict__ Qp)
{
    const int b = blockIdx.x;
    const int c = threadIdx.x;
    __shared__ float qs[1024];
    for (int k = threadIdx.x; k < 1024; k += 256) qs[k] = Q[b * 1024 + k];
    __syncthreads();
    float acc = 0.f;
    for (int d = 0; d < 1024; ++d) acc += qs[d] * Wq[d * 256 + c];
    Qp[b * 256 + c] = acc + bq[c];
}

// ---------------- Xp = concat(X, X[:,:, :4]) @ Wv + bv + Qp : [4][256][256] ----------------
__global__ __launch_bounds__(256) void xp_kernel(
    const float* __restrict__ X, const float* __restrict__ Wv,
    const float* __restrict__ bv, const float* __restrict__ Qp,
    float* __restrict__ Xp)
{
    const int rt = blockIdx.x;            // 0..63  (b, 16-row tile)
    const int ct = blockIdx.y;            // 0..3   (64-col tile)
    const int b = rt >> 4;
    const int n0 = (rt & 15) * 16;
    const int tid = threadIdx.x;
    const int c = ct * 64 + (tid & 63);
    const int rg = tid >> 6;              // 0..3 row group

    __shared__ float xs[16][512];
    float acc0 = 0.f, acc1 = 0.f, acc2 = 0.f, acc3 = 0.f;

    for (int d0 = 0; d0 < 2056; d0 += 512) {
        const int len = (d0 + 512 <= 2056) ? 512 : (2056 - d0);
        __syncthreads();
        if (len == 512) {
            for (int it = tid; it < 16 * 512; it += 256) {
                int r = it >> 9, d = it & 511;
                int dd = d0 + d;
                int dsrc = dd < 2052 ? dd : dd - 2052;
                xs[r][d] = X[((b * NR) + (n0 + r)) * 2052 + dsrc];
            }
        } else {                            // len == 8
            for (int it = tid; it < 16 * 8; it += 256) {
                int r = it >> 3, d = it & 7;
                int dd = d0 + d;
                int dsrc = dd < 2052 ? dd : dd - 2052;
                xs[r][d] = X[((b * NR) + (n0 + r)) * 2052 + dsrc];
            }
        }
        __syncthreads();
        const float* wp = Wv + (size_t)d0 * 256 + c;
        for (int d = 0; d < len; ++d) {
            float wv = wp[(size_t)d * 256];
            acc0 += xs[rg * 4 + 0][d] * wv;
            acc1 += xs[rg * 4 + 1][d] * wv;
            acc2 += xs[rg * 4 + 2][d] * wv;
            acc3 += xs[rg * 4 + 3][d] * wv;
        }
    }
    const float base = Qp[b * 256 + c] + bv[c];
    Xp[((b * NR) + (n0 + rg * 4 + 0)) * CC + c] = acc0 + base;
    Xp[((b * NR) + (n0 + rg * 4 + 1)) * CC + c] = acc1 + base;
    Xp[((b * NR) + (n0 + rg * 4 + 2)) * CC + c] = acc2 + base;
    Xp[((b * NR) + (n0 + rg * 4 + 3)) * CC + c] = acc3 + base;
}

// ---------------- pack weights into MFMA B-fragment layout (bf16) ----------------
// wpa layout: [br][nt(8)][ks(8)][lane(64)][e(8)]  value = W[c=ks*32+(l>>4)*8+e][n=nt*16+(l&15)]
// wpb layout: [br][nt(4)][ks(4)][lane(64)][e(8)]
__global__ __launch_bounds__(256) void pack_kernel(
    const float* __restrict__ W01, const float* __restrict__ W1,
    const float* __restrict__ W02, const float* __restrict__ W2,
    unsigned short* __restrict__ wpa, unsigned short* __restrict__ wpb)
{
    int t = blockIdx.x * 256 + threadIdx.x;
    if (t < 65536) {
        int e = t & 7, l = (t >> 3) & 63, ks = (t >> 9) & 7, nt = (t >> 12) & 7, br = (t >> 15) & 1;
        int cc = ks * 32 + (l >> 4) * 8 + e;
        int n = nt * 16 + (l & 15);
        const float* W = br ? W1 : W01;
        wpa[t] = f2bf(W[cc * 128 + n]);
    } else {
        int t2 = t - 65536;   // < 16384
        int e = t2 & 7, l = (t2 >> 3) & 63, ks = (t2 >> 9) & 3, nt = (t2 >> 11) & 3, br = (t2 >> 13) & 1;
        int cc = ks * 32 + (l >> 4) * 8 + e;
        int n = nt * 16 + (l & 15);
        const float* W = br ? W2 : W02;
        wpb[t2] = f2bf(W[cc * 64 + n]);
    }
}

// ---------------- the heavy kernel: fused 3-layer MLP over all pairs ----------------
// grid (64, 4): blockIdx.x = i-group (4 i's), blockIdx.y = b. 4 waves, wave = one i.
__global__ __launch_bounds__(256, 1) void pairs_kernel(
    const float* __restrict__ Xp,
    const unsigned short* __restrict__ wpa,
    const unsigned short* __restrict__ wpb,
    const float* __restrict__ b01, const float* __restrict__ b02,
    const float* __restrict__ W03, const float* __restrict__ b03,
    const float* __restrict__ b1,  const float* __restrict__ b2,
    const float* __restrict__ W3,  const float* __restrict__ b3,
    float* __restrict__ hout)
{
    __shared__ __align__(16) unsigned short lds_wa[32768];          // 64 KB (one branch)
    __shared__ __align__(16) unsigned short lds_wb[8192];           // 16 KB
    __shared__ __align__(16) float lds_si[1024];                    // 4 KB: Xp rows i0..i0+3
    __shared__ __align__(16) unsigned short lds_h1[4][2][16][136];  // 34 KB (per-wave private)
    __shared__ __align__(16) unsigned short lds_h2[4][2][16][72];   // 18 KB (per-wave private)
    __shared__ float lds_bias1[128];
    __shared__ float lds_bias2[64];
    __shared__ float lds_w3[64];

    const int tid = threadIdx.x;
    const int wave = tid >> 6;
    const int lane = tid & 63;
    const int b = blockIdx.y;
    const int ig = blockIdx.x;
    const int i = ig * 4 + wave;

    // stage scale rows Xp[b, ig*4 .. ig*4+3, :]
    #pragma unroll
    for (int k = 0; k < 4; ++k) {
        int idx = k * 256 + tid;
        int row = idx >> 8, c = idx & 255;
        lds_si[idx] = Xp[((b * NR) + (ig * 4 + row)) * CC + c];
    }

    const int row16 = lane & 15;
    const int kgrp = lane >> 4;       // 0..3
    const int rbase = kgrp * 4;

    for (int br = 0; br < 2; ++br) {
        // ---- stage this branch's packed weights + biases into LDS ----
        {
            const uint4* g = (const uint4*)(wpa + br * 32768);
            uint4* s = (uint4*)lds_wa;
            #pragma unroll
            for (int k = 0; k < 16; ++k) s[k * 256 + tid] = g[k * 256 + tid];
            const uint4* g2 = (const uint4*)(wpb + br * 8192);
            uint4* s2 = (uint4*)lds_wb;
            #pragma unroll
            for (int k = 0; k < 4; ++k) s2[k * 256 + tid] = g2[k * 256 + tid];
            if (tid < 128) lds_bias1[tid] = br ? b1[tid] : b01[tid];
            if (tid < 64)  lds_bias2[tid] = br ? b2[tid] : b02[tid];
            if (tid < 64)  lds_w3[tid]   = br ? W3[tid]  : W03[tid];
        }
        __syncthreads();
        const float b3v = br ? b3[0] : b03[0];

        for (int jg = 0; jg < 8; ++jg) {
            const int j0 = jg * 32;

            // ---- build A-fragments: P[i, j, :] in bf16, 2 m-tiles x 8 k-steps ----
            short8 afr[2][8];
            const float* si = lds_si + wave * 256;
            #pragma unroll
            for (int m = 0; m < 2; ++m) {
                const float* xr = Xp + ((size_t)(b * NR) + (j0 + m * 16 + row16)) * CC;
                #pragma unroll
                for (int ks = 0; ks < 8; ++ks) {
                    const int c0 = ks * 32 + kgrp * 8;
                    float4 xa = *(const float4*)(xr + c0);
                    float4 xb = *(const float4*)(xr + c0 + 4);
                    float4 sa = *(const float4*)(si + c0);
                    float4 sb = *(const float4*)(si + c0 + 4);
                    short8 f;
                    f[0] = (short)f2bf(xa.x * sa.x);
                    f[1] = (short)f2bf(xa.y * sa.y);
                    f[2] = (short)f2bf(xa.z * sa.z);
                    f[3] = (short)f2bf(xa.w * sa.w);
                    f[4] = (short)f2bf(xb.x * sb.x);
                    f[5] = (short)f2bf(xb.y * sb.y);
                    f[6] = (short)f2bf(xb.z * sb.z);
                    f[7] = (short)f2bf(xb.w * sb.w);
                    afr[m][ks] = f;
                }
            }

            // ---- layer 1: [32 j] x [K=256] @ [256 x 128] ----
            f32x4 acc[2][8] = {};
            #pragma unroll
            for (int ks = 0; ks < 8; ++ks) {
                #pragma unroll
                for (int nt = 0; nt < 8; ++nt) {
                    short8 bf = ((const short8*)lds_wa)[(nt * 8 + ks) * 64 + lane];
                    acc[0][nt] = __builtin_amdgcn_mfma_f32_16x16x32_bf16(afr[0][ks], bf, acc[0][nt], 0, 0, 0);
                    acc[1][nt] = __builtin_amdgcn_mfma_f32_16x16x32_bf16(afr[1][ks], bf, acc[1][nt], 0, 0, 0);
                }
            }
            // bias + relu + stage h1 (per-wave private, no barrier)
            #pragma unroll
            for (int m = 0; m < 2; ++m) {
                #pragma unroll
                for (int nt = 0; nt < 8; ++nt) {
                    const float bias = lds_bias1[nt * 16 + row16];
                    #pragma unroll
                    for (int r = 0; r < 4; ++r) {
                        float v = acc[m][nt][r] + bias;
                        v = v > 0.f ? v : 0.f;
                        lds_h1[wave][m][rbase + r][nt * 16 + row16] = f2bf(v);
                    }
                }
            }

            // ---- layer 2: [32 j] x [K=128] @ [128 x 64] ----
            f32x4 acc2[2][4] = {};
            #pragma unroll
            for (int ks = 0; ks < 4; ++ks) {
                short8 a2_0 = *(const short8*)&lds_h1[wave][0][row16][ks * 32 + kgrp * 8];
                short8 a2_1 = *(const short8*)&lds_h1[wave][1][row16][ks * 32 + kgrp * 8];
                #pragma unroll
                for (int nt = 0; nt < 4; ++nt) {
                    short8 bf = ((const short8*)lds_wb)[(nt * 4 + ks) * 64 + lane];
                    acc2[0][nt] = __builtin_amdgcn_mfma_f32_16x16x32_bf16(a2_0, bf, acc2[0][nt], 0, 0, 0);
                    acc2[1][nt] = __builtin_amdgcn_mfma_f32_16x16x32_bf16(a2_1, bf, acc2[1][nt], 0, 0, 0);
                }
            }
            // bias + relu + stage h2
            #pragma unroll
            for (int m = 0; m < 2; ++m) {
                #pragma unroll
                for (int nt = 0; nt < 4; ++nt) {
                    const float bias = lds_bias2[nt * 16 + row16];
                    #pragma unroll
                    for (int r = 0; r < 4; ++r) {
                        float v = acc2[m][nt][r] + bias;
                        v = v > 0.f ? v : 0.f;
                        lds_h2[wave][m][rbase + r][nt * 16 + row16] = f2bf(v);
                    }
                }
            }

            // ---- layer 3 (VALU dot with w3, K=64) ----
            const int jl = lane >> 1, half = lane & 1;
            const int m3 = jl >> 4, j3 = jl & 15;
            float dot = 0.f;
            #pragma unroll
            for (int qq = 0; qq < 4; ++qq) {
                uint4 u = *(const uint4*)&lds_h2[wave][m3][j3][half * 32 + qq * 8];
                const unsigned short* pu = (const unsigned short*)&u;
                #pragma unroll
                for (int e = 0; e < 8; ++e)
                    dot += bf2f(pu[e]) * lds_w3[half * 32 + qq * 8 + e];
            }
            dot += __shfl_xor(dot, 1, 64);
            if (half == 0) {
                float h3 = dot + b3v;
                h3 = h3 > 0.f ? h3 : 0.f;
                hout[(((br * 4 + b) * NR) + i) * NR + j0 + jl] = h3;
            }
        }
        __syncthreads();   // all waves done with this branch's weights
    }
}

// ---------------- column-softmax weights: w[j] = sum_i softmax(2h)[i,j] ----------------
__global__ __launch_bounds__(256) void colsoft_kernel(
    const float* __restrict__ h, float* __restrict__ wn)
{
    const int blk = blockIdx.x;                      // 0..7 = br*4+b
    const float* hb = h + ((size_t)blk << 16);
    const int j = threadIdx.x;
    __shared__ float red[256];

    float mx = -1e30f;
    for (int i2 = 0; i2 < NR; ++i2) mx = fmaxf(mx, hb[i2 * NR + j]);
    red[j] = mx; __syncthreads();
    for (int s = 128; s > 0; s >>= 1) {
        if (j < s) red[j] = fmaxf(red[j], red[j + s]);
        __syncthreads();
    }
    const float M = 2.f * red[0];
    __syncthreads();

    float cs = 0.f;
    for (int i2 = 0; i2 < NR; ++i2) cs += expf(2.f * hb[i2 * NR + j] - M);
    red[j] = cs; __syncthreads();
    for (int s = 128; s > 0; s >>= 1) {
        if (j < s) red[j] += red[j + s];
        __syncthreads();
    }
    const float Z = red[0];
    wn[blk * NR + j] = cs / Z;
}

// ---------------- out[b,d] = sum_j 0.5*(w0[j]+w1[j]) * X[b,j,d] ----------------
__global__ __launch_bounds__(256) void agg_kernel(
    const float* __restrict__ X, const float* __restrict__ wn,
    float* __restrict__ out)
{
    const int b = blockIdx.y;
    const int d = blockIdx.x * 256 + threadIdx.x;
    __shared__ float wc[256];
    const int j = threadIdx.x;
    wc[j] = 0.5f * (wn[b * NR + j] + wn[(4 + b) * NR + j]);
    __syncthreads();
    if (d < 2052) {
        float acc = 0.f;
        for (int jj = 0; jj < NR; ++jj) acc += wc[jj] * X[((b * NR) + jj) * 2052 + d];
        out[b * 2052 + d] = acc;
    }
}

extern "C" void kernel_launch(void* const* d_in, const int* in_sizes, int n_in,
                              void* d_out, int out_size, void* d_ws, size_t ws_size,
                              hipStream_t stream) {
    const float* Q   = (const float*)d_in[0];
    const float* X   = (const float*)d_in[1];
    const float* Wv  = (const float*)d_in[2];
    const float* bv  = (const float*)d_in[3];
    const float* Wq  = (const float*)d_in[4];
    const float* bq  = (const float*)d_in[5];
    const float* W01 = (const float*)d_in[6];
    const float* b01 = (const float*)d_in[7];
    const float* W02 = (const float*)d_in[8];
    const float* b02 = (const float*)d_in[9];
    const float* W03 = (const float*)d_in[10];
    const float* b03 = (const float*)d_in[11];
    const float* W1  = (const float*)d_in[12];
    const float* b1  = (const float*)d_in[13];
    const float* W2  = (const float*)d_in[14];
    const float* b2  = (const float*)d_in[15];
    const float* W3  = (const float*)d_in[16];
    const float* b3  = (const float*)d_in[17];

    float* wsf  = (float*)d_ws;
    float* Xp   = wsf;                 // 262144 f32
    float* Qp   = wsf + 262144;        // 1024 f32
    float* hbuf = wsf + 263168;        // 524288 f32: [2][4][256][256]
    float* wn   = wsf + 787456;        // 2048 f32: [2][4][256]
    unsigned short* wpa = (unsigned short*)((char*)d_ws + 3158016); // 65536 bf16
    unsigned short* wpb = (unsigned short*)((char*)d_ws + 3289088); // 16384 bf16
    float* out = (float*)d_out;

    qp_kernel<<<4, 256, 0, stream>>>(Q, Wq, bq, Qp);
    xp_kernel<<<dim3(64, 4), 256, 0, stream>>>(X, Wv, bv, Qp, Xp);
    pack_kernel<<<320, 256, 0, stream>>>(W01, W1, W02, W2, wpa, wpb);
    pairs_kernel<<<dim3(64, 4), 256, 0, stream>>>(Xp, wpa, wpb, b01, b02, W03, b03,
                                                  b1, b2, W3, b3, hbuf);
    colsoft_kernel<<<8, 256, 0, stream>>>(hbuf, wn);
    agg_kernel<<<dim3(9, 4), 256, 0, stream>>>(X, wn, out);
}

// Round 2
// 139.163 us; speedup vs baseline: 2.0471x; 2.0471x over previous
//
#include <hip/hip_runtime.h>
#include <hip/hip_bf16.h>

typedef __attribute__((ext_vector_type(8))) short short8;
typedef __attribute__((ext_vector_type(4))) float f32x4;

#define NR 256
#define CC 256

__device__ __forceinline__ unsigned short f2bf(float x) {
    union { float f; unsigned int u; } v; v.f = x;
    unsigned int r = v.u + 0x7FFFu + ((v.u >> 16) & 1u);
    return (unsigned short)(r >> 16);
}

__device__ __forceinline__ unsigned int pk2bf(float a, float b) {
    __hip_bfloat162 h = __float22bfloat162_rn(make_float2(a, b));
    union { __hip_bfloat162 h; unsigned int u; } cv; cv.h = h;
    return cv.u;
}

// ---------------- Qpp[ksl][b][n] = partial Q @ Wq ----------------
__global__ __launch_bounds__(256) void qp_kernel(
    const float* __restrict__ Q, const float* __restrict__ Wq,
    float* __restrict__ Qpp)
{
    const int ksl = blockIdx.x, b = blockIdx.y;
    const int n = threadIdx.x;
    __shared__ float qs[256];
    qs[n] = Q[b * 1024 + ksl * 256 + n];
    __syncthreads();
    float acc = 0.f;
    #pragma unroll 4
    for (int d = 0; d < 256; ++d) acc += qs[d] * Wq[(size_t)(ksl * 256 + d) * 256 + n];
    Qpp[(ksl * 4 + b) * 256 + n] = acc;
}

// ---------------- pack Wv into MFMA B-frag layout (bf16), K padded to 2080 ----------------
// wvp: [ks(65)][nt(16)][lane(64)][e(8)]  value = Wv[c=32ks+8*(l>>4)+e][n=16nt+(l&15)], 0 if c>=2056
__global__ __launch_bounds__(256) void wvp_pack_kernel(
    const float* __restrict__ Wv, unsigned short* __restrict__ wvp)
{
    __shared__ float tile[32][260];
    const int ks = blockIdx.x;   // 0..64
    const int tid = threadIdx.x;
    for (int idx = tid; idx < 32 * 256; idx += 256) {
        int cr = idx >> 8, n = idx & 255;
        int c = ks * 32 + cr;
        tile[cr][n] = (c < 2056) ? Wv[(size_t)c * 256 + n] : 0.f;
    }
    __syncthreads();
    #pragma unroll
    for (int q = 0; q < 4; ++q) {
        int t2 = tid * 4 + q;
        int nt = t2 >> 6, l = t2 & 63;
        int gg = l >> 4, jj = l & 15;
        short8 s;
        #pragma unroll
        for (int e = 0; e < 8; ++e)
            s[e] = (short)f2bf(tile[gg * 8 + e][nt * 16 + jj]);
        *(short8*)&wvp[((size_t)(ks * 16 + nt) * 64 + l) * 8] = s;
    }
}

// ---------------- pack MLP weights into MFMA fragment layout (bf16) ----------------
// wpa: [br][nt(8)][ks(8)][lane(64)][e(8)]  value = W[c=32ks+8*(l>>4)+e][n=16nt+(l&15)]
// wpb: [br][nt(4)][ks(4)][lane(64)][e(8)]
__global__ __launch_bounds__(256) void pack_kernel(
    const float* __restrict__ W01, const float* __restrict__ W1,
    const float* __restrict__ W02, const float* __restrict__ W2,
    unsigned short* __restrict__ wpa, unsigned short* __restrict__ wpb)
{
    int t = blockIdx.x * 256 + threadIdx.x;
    if (t < 65536) {
        int e = t & 7, l = (t >> 3) & 63, ks = (t >> 9) & 7, nt = (t >> 12) & 7, br = (t >> 15) & 1;
        int cc = ks * 32 + (l >> 4) * 8 + e;
        int n = nt * 16 + (l & 15);
        const float* W = br ? W1 : W01;
        wpa[t] = f2bf(W[cc * 128 + n]);
    } else {
        int t2 = t - 65536;   // < 16384
        int e = t2 & 7, l = (t2 >> 3) & 63, ks = (t2 >> 9) & 3, nt = (t2 >> 11) & 3, br = (t2 >> 13) & 1;
        int cc = ks * 32 + (l >> 4) * 8 + e;
        int n = nt * 16 + (l & 15);
        const float* W = br ? W2 : W02;
        wpb[t2] = f2bf(W[cc * 64 + n]);
    }
}

// ---------------- Xp = concat(X, X[:,:,:4]) @ Wv + bv + bq + Qp  (MFMA, 8-wave split-K) ----------------
__global__ __launch_bounds__(512) void xp_kernel(
    const float* __restrict__ X, const unsigned short* __restrict__ wvp,
    const float* __restrict__ bv, const float* __restrict__ bq,
    const float* __restrict__ Qpp, float* __restrict__ Xp)
{
    __shared__ f32x4 red[8][4][65];   // padded: stride 260 words kills reduce-phase conflicts
    const int tid = threadIdx.x;
    const int w = tid >> 6;           // 0..7
    const int lane = tid & 63;
    const int g = lane >> 4, j16 = lane & 15;
    const int mt = blockIdx.x;        // 16-row tile
    const int bn = blockIdx.y;        // 64-col tile
    const int b  = blockIdx.z;

    const int i0 = mt * 16;
    const int n0 = bn * 64;
    const float* xrow = X + ((size_t)(b * NR) + (i0 + j16)) * 2052;

    f32x4 acc[4] = {};

    for (int ks = w; ks < 64; ks += 8) {
        const int c0 = ks * 32 + g * 8;
        float4 xa = *(const float4*)(xrow + c0);
        float4 xb = *(const float4*)(xrow + c0 + 4);
        union { short8 s; unsigned int u[4]; } af;
        af.u[0] = pk2bf(xa.x, xa.y);
        af.u[1] = pk2bf(xa.z, xa.w);
        af.u[2] = pk2bf(xb.x, xb.y);
        af.u[3] = pk2bf(xb.z, xb.w);
        #pragma unroll
        for (int nt = 0; nt < 4; ++nt) {
            short8 bf = ((const short8*)wvp)[(size_t)(ks * 16 + bn * 4 + nt) * 64 + lane];
            acc[nt] = __builtin_amdgcn_mfma_f32_16x16x32_bf16(af.s, bf, acc[nt], 0, 0, 0);
        }
    }
    if (w == 0) {  // ks = 64 tail: c 2048..2079; c>=2056 has zero weights
        float xv[8];
        #pragma unroll
        for (int e = 0; e < 8; ++e) {
            int q = g * 8 + e;
            int csrc = (q < 4) ? (2048 + q) : (q - 4);   // 2052..2055 -> X[...,:4]; pad reads garbage*0
            xv[e] = xrow[csrc];
        }
        union { short8 s; unsigned int u[4]; } af;
        af.u[0] = pk2bf(xv[0], xv[1]);
        af.u[1] = pk2bf(xv[2], xv[3]);
        af.u[2] = pk2bf(xv[4], xv[5]);
        af.u[3] = pk2bf(xv[6], xv[7]);
        #pragma unroll
        for (int nt = 0; nt < 4; ++nt) {
            short8 bf = ((const short8*)wvp)[(size_t)(64 * 16 + bn * 4 + nt) * 64 + lane];
            acc[nt] = __builtin_amdgcn_mfma_f32_16x16x32_bf16(af.s, bf, acc[nt], 0, 0, 0);
        }
    }
    #pragma unroll
    for (int nt = 0; nt < 4; ++nt) red[w][nt][lane] = acc[nt];
    __syncthreads();

    // 512 threads x 2 outputs: sum 8 partials, add bias+Qp, store
    {
        int nt = tid >> 7;           // 0..3
        int l  = tid & 63;
        int half = (tid >> 6) & 1;
        float r0 = 0.f, r1 = 0.f;
        #pragma unroll
        for (int ww = 0; ww < 8; ++ww) {
            f32x4 v = red[ww][nt][l];
            r0 += v[half * 2 + 0];
            r1 += v[half * 2 + 1];
        }
        int gg = l >> 4, jj = l & 15;
        int n = n0 + nt * 16 + jj;
        float base = bv[n] + bq[n] + Qpp[b * 256 + n] + Qpp[(4 + b) * 256 + n]
                   + Qpp[(8 + b) * 256 + n] + Qpp[(12 + b) * 256 + n];
        int row0 = i0 + gg * 4 + half * 2;
        Xp[((b * NR) + row0) * CC + n]       = r0 + base;
        Xp[((b * NR) + row0 + 1) * CC + n]   = r1 + base;
    }
}

// ---------------- fused 3-layer MLP over pairs, upper-tri tiles, swapped-operand MFMA ----------------
// block = (b, it, jt): 4 waves (wave = one i = it*4+wave), j-tile of 32. Only jt >= it/8 launched.
__global__ __launch_bounds__(256, 2) void pairs_kernel(
    const float* __restrict__ Xp,
    const unsigned short* __restrict__ wpa,
    const unsigned short* __restrict__ wpb,
    const float* __restrict__ b01, const float* __restrict__ b02,
    const float* __restrict__ W03, const float* __restrict__ b03,
    const float* __restrict__ b1,  const float* __restrict__ b2,
    const float* __restrict__ W3,  const float* __restrict__ b3,
    float* __restrict__ hout)
{
    __shared__ __align__(16) unsigned short lds_wa[32768];   // 64 KB: one branch's L1 weights
    __shared__ __align__(16) float lds_si[1024];             // 4 i-rows of Xp
    __shared__ __align__(16) float lds_bias1[128];
    __shared__ __align__(16) float lds_bias2[64];
    __shared__ __align__(16) float lds_w3[64];

    const int tid = threadIdx.x;
    const int wave = tid >> 6;
    const int lane = tid & 63;
    const int g = lane >> 4;
    const int j16 = lane & 15;

    // grid mapping: bx -> (b, it, jt) over upper-triangular tile set (288 per b)
    int bx = blockIdx.x;
    int b = bx / 288;
    int u = bx - b * 288;
    int k = 0, off = 0;
    while (u >= off + 8 * (8 - k)) { off += 8 * (8 - k); ++k; }
    int rel = u - off, wdt = 8 - k;
    int it = k * 8 + rel / wdt;
    int jt = k + rel % wdt;

    const int i = it * 4 + wave;
    const int j0 = jt * 32;

    // stage the 4 i-rows
    {
        int ww = tid >> 6, c4 = (tid & 63) * 4;
        *(float4*)&lds_si[ww * 256 + c4] =
            *(const float4*)&Xp[((b * NR) + (it * 4 + ww)) * CC + c4];
    }

    const float* xrow0 = Xp + ((size_t)(b * NR) + (j0 + j16)) * CC;
    const float* xrow1 = Xp + ((size_t)(b * NR) + (j0 + 16 + j16)) * CC;
    const float* si = lds_si + wave * 256;
    const int s0 = ((lane & 16) ? 32 : 0) + j16;   // source lane 2*(g&1)*16 + j16
    const int s1 = s0 + 16;
    const bool hi = (g >> 1);                      // lane >= 32 -> wants odd nt1

    for (int br = 0; br < 2; ++br) {
        __syncthreads();   // prior-branch reads done (and si staged, on br==0)
        {
            const uint4* gsrc = (const uint4*)(wpa + br * 32768);
            uint4* sdst = (uint4*)lds_wa;
            #pragma unroll
            for (int kk = 0; kk < 16; ++kk) sdst[kk * 256 + tid] = gsrc[kk * 256 + tid];
            if (tid < 128) lds_bias1[tid] = br ? b1[tid] : b01[tid];
            else if (tid < 192) lds_bias2[tid - 128] = br ? b2[tid - 128] : b02[tid - 128];
            else lds_w3[tid - 192] = br ? W3[tid - 192] : W03[tid - 192];
        }
        __syncthreads();
        const float b3v = br ? b3[0] : b03[0];

        // W2^T fragments in registers (same lane map as packed layout)
        short8 wbf[16];
        #pragma unroll
        for (int q = 0; q < 16; ++q)
            wbf[q] = ((const short8*)wpb)[(br * 16 + q) * 64 + lane];
        f32x4 w3v[4];
        #pragma unroll
        for (int nt2 = 0; nt2 < 4; ++nt2)
            w3v[nt2] = *(const f32x4*)&lds_w3[nt2 * 16 + g * 4];

        #pragma unroll
        for (int mj = 0; mj < 2; ++mj) {
            const float* xr = mj ? xrow1 : xrow0;

            // B-fragments of P^T: lane(g,j) holds si[c]*Xp[j][c], c = 32ks+8g+e
            short8 bfr[8];
            #pragma unroll
            for (int ks = 0; ks < 8; ++ks) {
                const int c0 = ks * 32 + g * 8;
                float4 xa = *(const float4*)(xr + c0);
                float4 xb = *(const float4*)(xr + c0 + 4);
                float4 sa = *(const float4*)(si + c0);
                float4 sb = *(const float4*)(si + c0 + 4);
                union { short8 s; unsigned int u[4]; } f;
                f.u[0] = pk2bf(xa.x * sa.x, xa.y * sa.y);
                f.u[1] = pk2bf(xa.z * sa.z, xa.w * sa.w);
                f.u[2] = pk2bf(xb.x * sb.x, xb.y * sb.y);
                f.u[3] = pk2bf(xb.z * sb.z, xb.w * sb.w);
                bfr[ks] = f.s;
            }

            // layer 1 (swapped): acc1[nt1] = h1^T tile, C-init = bias1
            f32x4 acc1[8];
            #pragma unroll
            for (int nt1 = 0; nt1 < 8; ++nt1)
                acc1[nt1] = *(const f32x4*)&lds_bias1[nt1 * 16 + g * 4];
            #pragma unroll
            for (int ks = 0; ks < 8; ++ks) {
                #pragma unroll
                for (int nt1 = 0; nt1 < 8; ++nt1) {
                    short8 wf = ((const short8*)lds_wa)[(nt1 * 8 + ks) * 64 + lane];
                    acc1[nt1] = __builtin_amdgcn_mfma_f32_16x16x32_bf16(wf, bfr[ks], acc1[nt1], 0, 0, 0);
                }
            }

            // layer 2 (swapped): per t, relu+pack 2 nt1 tiles, shuffle-exchange into B-frag, 4 MFMAs
            f32x4 acc2[4];
            #pragma unroll
            for (int nt2 = 0; nt2 < 4; ++nt2)
                acc2[nt2] = *(const f32x4*)&lds_bias2[nt2 * 16 + g * 4];
            #pragma unroll
            for (int t = 0; t < 4; ++t) {
                float e0 = fmaxf(acc1[2*t][0], 0.f),   e1 = fmaxf(acc1[2*t][1], 0.f);
                float e2 = fmaxf(acc1[2*t][2], 0.f),   e3 = fmaxf(acc1[2*t][3], 0.f);
                float o0 = fmaxf(acc1[2*t+1][0], 0.f), o1 = fmaxf(acc1[2*t+1][1], 0.f);
                float o2 = fmaxf(acc1[2*t+1][2], 0.f), o3 = fmaxf(acc1[2*t+1][3], 0.f);
                unsigned int uE0 = pk2bf(e0, e1), uE1 = pk2bf(e2, e3);
                unsigned int uO0 = pk2bf(o0, o1), uO1 = pk2bf(o2, o3);
                unsigned int aE0 = __shfl(uE0, s0, 64), aO0 = __shfl(uO0, s0, 64);
                unsigned int aE1 = __shfl(uE1, s0, 64), aO1 = __shfl(uO1, s0, 64);
                unsigned int bE0 = __shfl(uE0, s1, 64), bO0 = __shfl(uO0, s1, 64);
                unsigned int bE1 = __shfl(uE1, s1, 64), bO1 = __shfl(uO1, s1, 64);
                union { short8 s; unsigned int u[4]; } B2;
                B2.u[0] = hi ? aO0 : aE0;
                B2.u[1] = hi ? aO1 : aE1;
                B2.u[2] = hi ? bO0 : bE0;
                B2.u[3] = hi ? bO1 : bE1;
                #pragma unroll
                for (int nt2 = 0; nt2 < 4; ++nt2)
                    acc2[nt2] = __builtin_amdgcn_mfma_f32_16x16x32_bf16(wbf[nt2 * 4 + t], B2.s, acc2[nt2], 0, 0, 0);
            }

            // layer 3: per-lane partial dot over its 16 n2 values, reduce across groups
            float part = 0.f;
            #pragma unroll
            for (int nt2 = 0; nt2 < 4; ++nt2) {
                part += fmaxf(acc2[nt2][0], 0.f) * w3v[nt2][0];
                part += fmaxf(acc2[nt2][1], 0.f) * w3v[nt2][1];
                part += fmaxf(acc2[nt2][2], 0.f) * w3v[nt2][2];
                part += fmaxf(acc2[nt2][3], 0.f) * w3v[nt2][3];
            }
            part += __shfl_xor(part, 16, 64);
            part += __shfl_xor(part, 32, 64);
            float h3 = part + b3v;
            h3 = h3 > 0.f ? h3 : 0.f;

            const int jg = j0 + mj * 16 + j16;
            float* hb = hout + ((size_t)(br * 4 + b) << 16);
            if (g == 0 && jg >= i) hb[i * NR + jg] = h3;   // upper incl diag
            if (g == 1 && jg > i)  hb[jg * NR + i] = h3;   // mirror (lower)
        }
    }
}

// ---------------- w[j] = sum_i softmax(2h)[i,j]; h>=0 (ReLU) so max-shift is skippable ----------------
__global__ __launch_bounds__(256) void colsoft_kernel(
    const float* __restrict__ h, float* __restrict__ wn)
{
    const int blk = blockIdx.x;                      // 0..7 = br*4+b
    const float* hb = h + ((size_t)blk << 16);
    const int j = threadIdx.x;
    __shared__ float red[256];
    float cs = 0.f;
    #pragma unroll 4
    for (int i2 = 0; i2 < NR; ++i2) cs += __expf(2.f * hb[i2 * NR + j]);
    red[j] = cs; __syncthreads();
    for (int s = 128; s > 0; s >>= 1) {
        if (j < s) red[j] += red[j + s];
        __syncthreads();
    }
    wn[blk * NR + j] = cs / red[0];
}

// ---------------- out[b,d] = sum_j 0.5*(w0[j]+w1[j]) * X[b,j,d] ----------------
__global__ __launch_bounds__(256) void agg_kernel(
    const float* __restrict__ X, const float* __restrict__ wn,
    float* __restrict__ out)
{
    const int b = blockIdx.y;
    const int d = blockIdx.x * 256 + threadIdx.x;
    __shared__ float wc[256];
    const int j = threadIdx.x;
    wc[j] = 0.5f * (wn[b * NR + j] + wn[(4 + b) * NR + j]);
    __syncthreads();
    if (d < 2052) {
        float a0 = 0.f, a1 = 0.f, a2 = 0.f, a3 = 0.f;
        const float* xp = X + (size_t)b * NR * 2052 + d;
        for (int jj = 0; jj < NR; jj += 4) {
            a0 += wc[jj + 0] * xp[(size_t)(jj + 0) * 2052];
            a1 += wc[jj + 1] * xp[(size_t)(jj + 1) * 2052];
            a2 += wc[jj + 2] * xp[(size_t)(jj + 2) * 2052];
            a3 += wc[jj + 3] * xp[(size_t)(jj + 3) * 2052];
        }
        out[b * 2052 + d] = (a0 + a1) + (a2 + a3);
    }
}

extern "C" void kernel_launch(void* const* d_in, const int* in_sizes, int n_in,
                              void* d_out, int out_size, void* d_ws, size_t ws_size,
                              hipStream_t stream) {
    const float* Q   = (const float*)d_in[0];
    const float* X   = (const float*)d_in[1];
    const float* Wv  = (const float*)d_in[2];
    const float* bv  = (const float*)d_in[3];
    const float* Wq  = (const float*)d_in[4];
    const float* bq  = (const float*)d_in[5];
    const float* W01 = (const float*)d_in[6];
    const float* b01 = (const float*)d_in[7];
    const float* W02 = (const float*)d_in[8];
    const float* b02 = (const float*)d_in[9];
    const float* W03 = (const float*)d_in[10];
    const float* b03 = (const float*)d_in[11];
    const float* W1  = (const float*)d_in[12];
    const float* b1  = (const float*)d_in[13];
    const float* W2  = (const float*)d_in[14];
    const float* b2  = (const float*)d_in[15];
    const float* W3  = (const float*)d_in[16];
    const float* b3  = (const float*)d_in[17];

    char* ws = (char*)d_ws;
    // byte layout (all 16B aligned); wvp aliases hbuf (dead before pairs writes hbuf)
    float* Xp   = (float*)(ws + 0);              // 1,048,576 B
    float* Qpp  = (float*)(ws + 1048576);        //    16,384 B
    float* wn   = (float*)(ws + 1064960);        //     8,192 B
    unsigned short* wpa = (unsigned short*)(ws + 1073152);  // 131,072 B
    unsigned short* wpb = (unsigned short*)(ws + 1204224);  //  32,768 B
    float* hbuf = (float*)(ws + 1236992);        // 2,097,152 B -> end 3,334,144
    unsigned short* wvp = (unsigned short*)(ws + 1236992);  // 1,064,960 B (aliased)
    float* out = (float*)d_out;

    qp_kernel<<<dim3(4, 4), 256, 0, stream>>>(Q, Wq, Qpp);
    wvp_pack_kernel<<<65, 256, 0, stream>>>(Wv, wvp);
    pack_kernel<<<320, 256, 0, stream>>>(W01, W1, W02, W2, wpa, wpb);
    xp_kernel<<<dim3(16, 4, 4), 512, 0, stream>>>(X, wvp, bv, bq, Qpp, Xp);
    pairs_kernel<<<1152, 256, 0, stream>>>(Xp, wpa, wpb, b01, b02, W03, b03,
                                           b1, b2, W3, b3, hbuf);
    colsoft_kernel<<<8, 256, 0, stream>>>(hbuf, wn);
    agg_kernel<<<dim3(9, 4), 256, 0, stream>>>(X, wn, out);
}